// Round 1
// baseline (155.235 us; speedup 1.0000x reference)
//
#include <hip/hip_runtime.h>

#define NN 512   // N
#define DD 16    // D (16 floats = 4 float4)

// One block per (b, i) output row. Block = 512 threads (8 waves).
// LDS: messages for batch b (32 KiB) + coef row (2 KiB) + neighbor idx (2 KiB).
__global__ __launch_bounds__(512) void graph_layer_kernel(
    const int*    __restrict__ adj,    // [B][N][N] int32
    const float*  __restrict__ coef,   // [B][N][N] fp32
    const float4* __restrict__ msg4,   // [B][N][4] (= [B][N][16] fp32)
    float4*       __restrict__ out4)   // [B][N][N*4] (= [B][N][N*16] fp32)
{
    __shared__ float4 smsg[NN * 4];    // 32 KiB: messages of this batch
    __shared__ float  scoef[NN];       // 2 KiB
    __shared__ int    snb[NN];         // compacted valid-column indices
    __shared__ int    wtot[8];         // per-wave valid counts

    const int row  = blockIdx.x;       // b*N + i
    const int b    = row >> 9;
    const int i    = row & (NN - 1);
    const int t    = threadIdx.x;
    const int lane = t & 63;
    const int wv   = t >> 6;

    // --- stage coef row (coalesced) ---
    scoef[t] = coef[(size_t)row * NN + t];

    // --- stage this batch's messages (coalesced float4, 32 KiB) ---
    {
        const float4* src = msg4 + (size_t)b * (NN * 4);
        #pragma unroll
        for (int k = 0; k < 4; ++k)
            smsg[t + k * 512] = src[t + k * 512];
    }

    // --- general neighbor compaction: sort(where(valid, cols, n))[:n-1] ---
    // stable ascending compaction of valid columns; fill = n clamped to n-1
    const int  a     = adj[(size_t)row * NN + t];
    const bool valid = (a != -1);
    const unsigned long long m = __ballot(valid);
    const int  rank  = __popcll(m & ((1ULL << lane) - 1ULL));
    snb[t] = NN - 1;                   // JAX out-of-bounds gather clamps n -> n-1
    if (lane == 0) wtot[wv] = __popcll(m);
    __syncthreads();

    int base = 0;
    #pragma unroll
    for (int w = 0; w < 8; ++w)
        base += (w < wv) ? wtot[w] : 0;
    if (valid) {
        const int pos = base + rank;
        if (pos < NN) snb[pos] = t;
    }
    __syncthreads();

    // --- produce the output row: 8192 floats = 2048 float4, coalesced ---
    float4* orow = out4 + (size_t)row * (NN * 4);
    #pragma unroll
    for (int k = 0; k < 4; ++k) {
        const int g = t + k * 512;     // float4 index within the row
        const int j = g >> 2;          // output column (which neighbor slot)
        const int q = g & 3;           // which float4 of the D=16 message
        const int s = (j == 0) ? i : snb[j - 1];
        const float c = scoef[j];
        const float4 v = smsg[s * 4 + q];
        float4 o;
        o.x = c * v.x; o.y = c * v.y; o.z = c * v.z; o.w = c * v.w;
        orow[g] = o;
    }
}

extern "C" void kernel_launch(void* const* d_in, const int* in_sizes, int n_in,
                              void* d_out, int out_size, void* d_ws, size_t ws_size,
                              hipStream_t stream) {
    const int*    adj  = (const int*)d_in[0];     // adj_matrix (int32)
    const float*  coef = (const float*)d_in[1];   // adj_coef
    const float4* msg4 = (const float4*)d_in[2];  // neighbour_messages
    float4*       out4 = (float4*)d_out;          // fp32 output

    const int B = 8;
    graph_layer_kernel<<<B * NN, 512, 0, stream>>>(adj, coef, msg4, out4);
}